// Round 13
// baseline (155.306 us; speedup 1.0000x reference)
//
#include <hip/hip_runtime.h>
#include <hip/hip_bf16.h>

#define DEVI __device__ __forceinline__

typedef __bf16 bf16x8 __attribute__((ext_vector_type(8)));
typedef float f32x4 __attribute__((ext_vector_type(4)));

DEVI unsigned short f2bf(float x) {
    union { __hip_bfloat16 h; unsigned short u; } v;
    v.h = __float2bfloat16(x);
    return v.u;
}

DEVI float exp2_fast(float x) {
#if __has_builtin(__builtin_amdgcn_exp2f)
    return __builtin_amdgcn_exp2f(x);
#else
    return exp2f(x);
#endif
}

DEVI void gload16(const void* gsrc, void* lds) {
    __builtin_amdgcn_global_load_lds(
        (const __attribute__((address_space(1))) void*)gsrc,
        (__attribute__((address_space(3))) void*)lds,
        16, 0, 0);
}

#define BARRIER_MEM() asm volatile("s_barrier" ::: "memory")
#define WAITVM(n) asm volatile("s_waitcnt vmcnt(" #n ")" ::: "memory")
#define LGKM0() asm volatile("s_waitcnt lgkmcnt(0)" ::: "memory")

// ---------------- conversion / transpose kernels ----------------

__global__ __launch_bounds__(256) void convert_f32_bf16_vec(
    const float* __restrict__ in, unsigned short* __restrict__ out, int n4) {
    int i = blockIdx.x * 256 + threadIdx.x;
    if (i >= n4) return;
    float4 v = reinterpret_cast<const float4*>(in)[i];
    ushort4 o;
    o.x = f2bf(v.x); o.y = f2bf(v.y); o.z = f2bf(v.z); o.w = f2bf(v.w);
    reinterpret_cast<ushort4*>(out)[i] = o;
}

// dst[c][r] = bf16(src[r][c]) for Wq/Wk/Wv (1024x1024), selected by blockIdx.z
__global__ __launch_bounds__(256) void transpose_wqkv(
    const float* __restrict__ wq, const float* __restrict__ wk,
    const float* __restrict__ wv, unsigned short* __restrict__ dst) {
    __shared__ unsigned short tile[32][33];
    const float* src = (blockIdx.z == 0) ? wq : (blockIdx.z == 1) ? wk : wv;
    unsigned short* d = dst + blockIdx.z * 1024 * 1024;
    int c0 = blockIdx.x * 32, r0 = blockIdx.y * 32;
    int tx = threadIdx.x & 31, ty = threadIdx.x >> 5;
    #pragma unroll
    for (int i = ty; i < 32; i += 8)
        tile[tx][i] = f2bf(src[(r0 + i) * 1024 + c0 + tx]);
    __syncthreads();
    #pragma unroll
    for (int i = ty; i < 32; i += 8)
        d[(c0 + i) * 1024 + r0 + tx] = tile[i][tx];
}

// dst[c][r] = bf16(src[r][c]); src is [R][Cc] fp32. grid (Cc/32, R/32), 256 thr.
__global__ __launch_bounds__(256) void transpose_f32_to_bf16t(
    const float* __restrict__ src, unsigned short* __restrict__ dst,
    int R, int Cc) {
    __shared__ unsigned short tile[32][33];
    int c0 = blockIdx.x * 32, r0 = blockIdx.y * 32;
    int tx = threadIdx.x & 31, ty = threadIdx.x >> 5;
    #pragma unroll
    for (int i = ty; i < 32; i += 8)
        tile[tx][i] = f2bf(src[(r0 + i) * Cc + c0 + tx]);
    __syncthreads();
    #pragma unroll
    for (int i = ty; i < 32; i += 8)
        dst[(c0 + i) * R + r0 + tx] = tile[i][tx];
}

// ---------------- gemm256 v2: 256x192 tile, BK=64, single-barrier K-loop ----
// C[8192,3072] = A[8192,1024] * Bt[3072,1024]^T. 512 blocks = 2 exact dispatch
// rounds. 8 waves (4M x 2N), per-wave 64x96 = acc[4][6]. LDS 112 KiB double
// buffer, XOR-swizzled.
__global__ __launch_bounds__(512, 2) void gemm256(
    const unsigned short* __restrict__ A, const unsigned short* __restrict__ Bt,
    unsigned short* __restrict__ q_out, unsigned short* __restrict__ k_out,
    unsigned short* __restrict__ v_out) {
    __shared__ unsigned short Ab[2][256 * 64];
    __shared__ unsigned short Bb[2][192 * 64];

    const int wg = (blockIdx.x & 7) * 64 + (blockIdx.x >> 3);
    const int bm = (wg >> 4) << 8;       // 32 M-tiles of 256
    const int bn = (wg & 15) * 192;      // 16 N-tiles of 192

    const int tid = threadIdx.x;
    const int w = tid >> 6, l = tid & 63;
    const int wm = w >> 1, wn = w & 1;   // 4M x 2N
    const int lc = l & 15, lg = l >> 4;
    const int lr8 = l >> 3;
    const int colsw = 8 * ((l & 7) ^ lr8);   // inverse-swizzled src chunk

    const unsigned short* gA = A + (size_t)(bm + lr8) * 1024 + colsw;
    const unsigned short* gB = Bt + (size_t)(bn + lr8) * 1024 + colsw;

    const int p16_0 = (lg ^ (lc & 7)) * 16;
    const int p16_1 = ((4 | lg) ^ (lc & 7)) * 16;

    auto STAGE = [&](int bufn, int tt) {
        #pragma unroll
        for (int j = 0; j < 4; ++j) {
            const int r0 = j * 64 + w * 8;
            gload16(gA + (size_t)r0 * 1024 + tt * 64,
                    (char*)&Ab[bufn][0] + r0 * 128);
        }
        #pragma unroll
        for (int j = 0; j < 3; ++j) {
            const int r0 = j * 64 + w * 8;
            gload16(gB + (size_t)r0 * 1024 + tt * 64,
                    (char*)&Bb[bufn][0] + r0 * 128);
        }
    };

    bf16x8 a[4][2], b[6][2];
    f32x4 acc[4][6] = {};
    const int nt = 16;   // K = 1024 / 64

    STAGE(0, 0);

    #pragma unroll 1
    for (int t = 0; t < nt; ++t) {
        const int buf = t & 1;
        WAITVM(0);
        LGKM0();
        BARRIER_MEM();
        if (t + 1 < nt) STAGE(buf ^ 1, t + 1);

        const char* Arow = (const char*)&Ab[buf][0] + (wm * 64 + lc) * 128;
        const char* Brow = (const char*)&Bb[buf][0] + (wn * 96 + lc) * 128;
        #pragma unroll
        for (int fi = 0; fi < 4; ++fi) {
            a[fi][0] = *(const bf16x8*)(Arow + fi * 16 * 128 + p16_0);
            a[fi][1] = *(const bf16x8*)(Arow + fi * 16 * 128 + p16_1);
        }
        #pragma unroll
        for (int ni = 0; ni < 6; ++ni) {
            b[ni][0] = *(const bf16x8*)(Brow + ni * 16 * 128 + p16_0);
            b[ni][1] = *(const bf16x8*)(Brow + ni * 16 * 128 + p16_1);
        }
        __builtin_amdgcn_s_setprio(1);
        #pragma unroll
        for (int fi = 0; fi < 4; ++fi)
            #pragma unroll
            for (int ni = 0; ni < 6; ++ni) {
                acc[fi][ni] = __builtin_amdgcn_mfma_f32_16x16x32_bf16(
                    a[fi][0], b[ni][0], acc[fi][ni], 0, 0, 0);
                acc[fi][ni] = __builtin_amdgcn_mfma_f32_16x16x32_bf16(
                    a[fi][1], b[ni][1], acc[fi][ni], 0, 0, 0);
            }
        __builtin_amdgcn_s_setprio(0);
    }

    // epilogue: per-ni column range (16 wide, never straddles 1024 boundary)
    #pragma unroll
    for (int ni = 0; ni < 6; ++ni) {
        const int n = bn + wn * 96 + ni * 16 + lc;
        const int which = n >> 10;
        const int rr = n & 1023;
        if (which == 2) {
            // V third: store directly transposed into v_t [bh][64][2048]
            #pragma unroll
            for (int fi = 0; fi < 4; ++fi) {
                const int m = bm + wm * 64 + fi * 16 + lg * 4;
                const int bhh = (m >> 11) * 16 + (rr >> 6);
                const int d = rr & 63;
                const int tt = m & 2047;
                ushort4 o;
                o.x = f2bf(acc[fi][ni][0]); o.y = f2bf(acc[fi][ni][1]);
                o.z = f2bf(acc[fi][ni][2]); o.w = f2bf(acc[fi][ni][3]);
                *reinterpret_cast<ushort4*>(
                    &v_out[((size_t)bhh * 64 + d) * 2048 + tt]) = o;
            }
        } else {
            unsigned short* dst = which ? k_out : q_out;
            #pragma unroll
            for (int fi = 0; fi < 4; ++fi)
                #pragma unroll
                for (int r = 0; r < 4; ++r) {
                    const int m = bm + wm * 64 + fi * 16 + lg * 4 + r;
                    dst[(size_t)m * 1024 + rr] = f2bf(acc[fi][ni][r]);
                }
        }
    }
}

// ---------------- GEMM: C[M,N] = A[M,K] * Bt[N,K]^T (bf16 in, fp32 acc) ------
// (kept for the small output projection, K=64)
template <int EPI>
__global__ __launch_bounds__(256) void gemm_bt(
    const unsigned short* __restrict__ A, const unsigned short* __restrict__ Bt,
    int Mdim, int Ndim, int Kdim,
    unsigned short* __restrict__ q_out, unsigned short* __restrict__ k_out,
    unsigned short* __restrict__ v_out, float* __restrict__ c_out) {
    __shared__ unsigned short As[128 * 32];
    __shared__ unsigned short Bs[128 * 32];
    const int ntn = Ndim >> 7;
    const int bm = (blockIdx.x / ntn) << 7;
    const int bn = (blockIdx.x % ntn) << 7;
    const int tid = threadIdx.x;
    const int w = tid >> 6, l = tid & 63;
    const int wr = w >> 1, wc = w & 1;
    const int lrow = l >> 2, lcb = (l & 3) * 8;
    const int lc = l & 15, lg = l >> 4;

    f32x4 acc[4][4] = {};

    for (int k0 = 0; k0 < Kdim; k0 += 32) {
        __syncthreads();
        #pragma unroll
        for (int i = 0; i < 2; ++i) {
            int j = w * 2 + i;
            gload16(A + (bm + j * 16 + lrow) * Kdim + k0 + lcb, (char*)As + j * 1024);
            gload16(Bt + (bn + j * 16 + lrow) * Kdim + k0 + lcb, (char*)Bs + j * 1024);
        }
        __syncthreads();
        bf16x8 af[4], bfr[4];
        #pragma unroll
        for (int mi = 0; mi < 4; ++mi)
            af[mi] = *reinterpret_cast<const bf16x8*>(&As[(wr * 64 + mi * 16 + lc) * 32 + lg * 8]);
        #pragma unroll
        for (int ni = 0; ni < 4; ++ni)
            bfr[ni] = *reinterpret_cast<const bf16x8*>(&Bs[(wc * 64 + ni * 16 + lc) * 32 + lg * 8]);
        #pragma unroll
        for (int mi = 0; mi < 4; ++mi)
            #pragma unroll
            for (int ni = 0; ni < 4; ++ni)
                acc[mi][ni] = __builtin_amdgcn_mfma_f32_16x16x32_bf16(
                    af[mi], bfr[ni], acc[mi][ni], 0, 0, 0);
    }

    #pragma unroll
    for (int mi = 0; mi < 4; ++mi) {
        #pragma unroll
        for (int ni = 0; ni < 4; ++ni) {
            #pragma unroll
            for (int r = 0; r < 4; ++r) {
                int m = bm + wr * 64 + mi * 16 + lg * 4 + r;
                int n = bn + wc * 64 + ni * 16 + lc;
                float val = acc[mi][ni][r];
                if (EPI == 0) {
                    int which = n >> 10, rr = n & 1023;
                    unsigned short* dst = (which == 0) ? q_out : (which == 1) ? k_out : v_out;
                    dst[m * 1024 + rr] = f2bf(val);
                } else {
                    c_out[m * Ndim + n] = val;
                }
            }
        }
    }
}

// ---------------- flash attention v6 ----------------------------------------
// Swapped-operand form: S^T = mfma(K,Q), O^T = mfma(V^T,P^T). Triple-buffered
// K/V, ONE barrier per k-tile, counted vmcnt(2). Static softmax. Causal
// pair-scheduling: 512 blocks x 8 waves x 16 q-rows, 34 tiles/block.
// (byte-identical to the round-8-PASSING binary; NaN-streak post-mortems
// r9-r12 could not exonerate any perturbation of this kernel, so it is
// restored verbatim as the green anchor.)
__global__ __launch_bounds__(512, 4) void attn_kernel(
    const unsigned short* __restrict__ qb, const unsigned short* __restrict__ kb,
    const unsigned short* __restrict__ vt, unsigned short* __restrict__ ypart) {
    __shared__ unsigned short Ks[3][64 * 64];
    __shared__ unsigned short Vs[3][64 * 64];
    __shared__ unsigned short plds[8][16 * 72];

    const int i = blockIdx.x;
    const int slot = i >> 3;
    const int bh = (i & 7) + ((slot >> 3) << 3);
    const int pr = slot & 7;
    const int b = bh >> 4, h = bh & 15;
    const int tid = threadIdx.x, w = tid >> 6, l = tid & 63;
    const int lc = l & 15, lg = l >> 4;

    const float SCL = 0.125f * 1.44269504f;  // 1/sqrt(64) * log2(e)

    const int rowc = l >> 3;
    const int colsw = 8 * ((l & 7) ^ rowc);
    const unsigned short* kbh = kb + (b * 2048) * 1024 + h * 64;
    const unsigned short* vbh = vt + bh * 64 * 2048;
    const int swz = (lc & 7) * 8;

    unsigned short* pl = &plds[w][0];

    auto STAGE = [&](int bufn, int kt) {
        const int tk0s = kt << 6;
        const int row = w * 8 + rowc;
        gload16(kbh + (tk0s + row) * 1024 + colsw, (char*)&Ks[bufn][0] + w * 1024);
        gload16(vbh + row * 2048 + tk0s + colsw, (char*)&Vs[bufn][0] + w * 1024);
    };

    auto run_pass = [&](int qblk) {
        const int q0 = qblk << 7;
        const int qrowW = q0 + w * 16;       // wave's 16 q-rows

        bf16x8 qf[2];
        {
            const unsigned short* qp =
                qb + (b * 2048 + qrowW + lc) * 1024 + h * 64;
            qf[0] = *reinterpret_cast<const bf16x8*>(qp + lg * 8);
            qf[1] = *reinterpret_cast<const bf16x8*>(qp + 32 + lg * 8);
        }

        f32x4 accO[4] = {};
        float lsum = 0.f;

        const int nkt = 2 * qblk + 2;
        STAGE(0, 0);
        STAGE(1, 1);
        int cur = 0;

        for (int kt = 0; kt < nkt; ++kt) {
            const int tk0 = kt << 6;
            if (kt + 1 < nkt) { WAITVM(2); } else { WAITVM(0); }
            BARRIER_MEM();      // all waves done computing tile kt-1; tile kt staged
            if (kt + 2 < nkt) {
                const int sb = (cur >= 1) ? cur - 1 : cur + 2;  // (kt+2)%3
                STAGE(sb, kt + 2);
            }

            if (tk0 <= qrowW + 15) {
                // ---- QK^T (swapped): s[ni] = S^T[k=tk0+16ni+4lg+r][q=qrowW+lc]
                f32x4 s[4] = {};
                #pragma unroll
                for (int ni = 0; ni < 4; ++ni) {
                    const unsigned short* kr = &Ks[cur][(ni * 16 + lc) * 64];
                    bf16x8 kf0 = *reinterpret_cast<const bf16x8*>(&kr[(lg * 8) ^ swz]);
                    bf16x8 kf1 = *reinterpret_cast<const bf16x8*>(&kr[(32 + lg * 8) ^ swz]);
                    s[ni] = __builtin_amdgcn_mfma_f32_16x16x32_bf16(kf0, qf[0], s[ni], 0, 0, 0);
                    s[ni] = __builtin_amdgcn_mfma_f32_16x16x32_bf16(kf1, qf[1], s[ni], 0, 0, 0);
                }
                // ---- scale + mask + exp + pack + P^T->LDS (4x b64) ----
                const bool needmask = (tk0 + 63 > qrowW);
                const int tq = qrowW + lc;
                #pragma unroll
                for (int ni = 0; ni < 4; ++ni) {
                    float pv[4];
                    #pragma unroll
                    for (int r = 0; r < 4; ++r) {
                        float sv = s[ni][r] * SCL;
                        if (needmask) {
                            int tk = tk0 + ni * 16 + lg * 4 + r;
                            sv = (tk > tq) ? -INFINITY : sv;
                        }
                        pv[r] = exp2_fast(sv);
                        lsum += pv[r];
                    }
                    unsigned int w0, w1;
                    asm("v_cvt_pk_bf16_f32 %0, %1, %2" : "=v"(w0) : "v"(pv[0]), "v"(pv[1]));
                    asm("v_cvt_pk_bf16_f32 %0, %1, %2" : "=v"(w1) : "v"(pv[2]), "v"(pv[3]));
                    uint2 pk2; pk2.x = w0; pk2.y = w1;
                    *reinterpret_cast<uint2*>(&pl[lc * 72 + ni * 16 + lg * 4]) = pk2;
                }
                // ---- P@V (swapped): accO[ni] = O^T[d=16ni+4lg+r][q=qrowW+lc]
                bf16x8 pf0 = *reinterpret_cast<const bf16x8*>(&pl[lc * 72 + lg * 8]);
                bf16x8 pf1 = *reinterpret_cast<const bf16x8*>(&pl[lc * 72 + 32 + lg * 8]);
                #pragma unroll
                for (int ni = 0; ni < 4; ++ni) {
                    const unsigned short* vr = &Vs[cur][(ni * 16 + lc) * 64];
                    bf16x8 vf0 = *reinterpret_cast<const bf16x8*>(&vr[(lg * 8) ^ swz]);
                    bf16x8 vf1 = *reinterpret_cast<const bf16x8*>(&vr[(32 + lg * 8) ^ swz]);
                    accO[ni] = __builtin_amdgcn_mfma_f32_16x16x32_bf16(vf0, pf0, accO[ni], 0, 0, 0);
                    accO[ni] = __builtin_amdgcn_mfma_f32_16x16x32_bf16(vf1, pf1, accO[ni], 0, 0, 0);
                }
            }
            cur = (cur + 1 == 3) ? 0 : cur + 1;
        }
        BARRIER_MEM();   // protect pass-2 re-staging of bufs 0/1

        // row-sum reduce (2 shuffles), then vectorized scaled store
        float tsum = lsum;
        tsum += __shfl_xor(tsum, 16);
        tsum += __shfl_xor(tsum, 32);
        const float rinv = 1.0f / tsum;
        const int tq = qrowW + lc;
        #pragma unroll
        for (int ni = 0; ni < 4; ++ni) {
            ushort4 o;
            o.x = f2bf(accO[ni][0] * rinv);
            o.y = f2bf(accO[ni][1] * rinv);
            o.z = f2bf(accO[ni][2] * rinv);
            o.w = f2bf(accO[ni][3] * rinv);
            *reinterpret_cast<ushort4*>(
                &ypart[(bh * 2048 + tq) * 64 + ni * 16 + lg * 4]) = o;
        }
    };

    run_pass(15 - pr);   // long pass first (primes L2 for the short pass)
    run_pass(pr);
}

// ---------------- head-sum reduce: y[m][d] = sum_h ypart[b][h][t][d] --------
__global__ __launch_bounds__(256) void reduce_heads(
    const unsigned short* __restrict__ ypart, unsigned short* __restrict__ yb) {
    int idx = blockIdx.x * 256 + threadIdx.x;  // < 8192*64
    int d = idx & 63, m = idx >> 6;
    int b = m >> 11, t = m & 2047;
    const unsigned short* p = ypart + ((b * 16) * 2048 + t) * 64 + d;
    float s = 0.f;
    #pragma unroll
    for (int h = 0; h < 16; ++h) {
        union { unsigned short u; __hip_bfloat16 h; } v;
        v.u = p[h * 2048 * 64];
        s += __bfloat162float(v.h);
    }
    yb[idx] = f2bf(s);
}

// ---------------- launcher ----------------

extern "C" void kernel_launch(void* const* d_in, const int* in_sizes, int n_in,
                              void* d_out, int out_size, void* d_ws, size_t ws_size,
                              hipStream_t stream) {
    const float* x  = (const float*)d_in[0];
    const float* Wq = (const float*)d_in[1];
    const float* Wk = (const float*)d_in[2];
    const float* Wv = (const float*)d_in[3];
    const float* Wp = (const float*)d_in[4];
    float* out = (float*)d_out;

    // workspace layout (bytes):
    //   [0, 16777216)      ypart bf16 [64][2048][64]  (aliases xb, phase 4+)
    //   [0, 16777216)      xb bf16 [8192][1024]       (phase 1 only)
    //   [33554432,39845888) wqkv_t bf16 [3072][1024]
    //   [39845888,39976960) wp_t bf16 [1024][64]
    //   [39976960,56754176) q_proj bf16
    //   [56754176,73531392) k_proj bf16
    //   [73531392,90308608) v_t bf16 [64][64][2048]   (written by gemm256)
    //   [90308608,91357184) y_b bf16 [8192][64]
    if (ws_size < 91357184) return;
    char* ws = (char*)d_ws;
    unsigned short* ypart = (unsigned short*)ws;
    unsigned short* xb   = (unsigned short*)ws;
    unsigned short* wt   = (unsigned short*)(ws + 33554432);
    unsigned short* wpt  = (unsigned short*)(ws + 39845888);
    unsigned short* qbf  = (unsigned short*)(ws + 39976960);
    unsigned short* kbf  = (unsigned short*)(ws + 56754176);
    unsigned short* vtb  = (unsigned short*)(ws + 73531392);
    unsigned short* yb   = (unsigned short*)(ws + 90308608);

    convert_f32_bf16_vec<<<8192, 256, 0, stream>>>(x, xb, 2097152);
    transpose_wqkv<<<dim3(32, 32, 3), 256, 0, stream>>>(Wq, Wk, Wv, wt);
    transpose_f32_to_bf16t<<<dim3(32, 2), 256, 0, stream>>>(Wp, wpt, 64, 1024);

    gemm256<<<512, 512, 0, stream>>>(xb, wt, qbf, kbf, vtb);

    attn_kernel<<<512, 512, 0, stream>>>(qbf, kbf, vtb, ypart);

    reduce_heads<<<2048, 256, 0, stream>>>(ypart, yb);

    gemm_bt<1><<<(8192 / 128) * (1024 / 128), 256, 0, stream>>>(
        yb, wpt, 8192, 1024, 64, nullptr, nullptr, nullptr, out);
}

// Round 14
// 149.552 us; speedup vs baseline: 1.0385x; 1.0385x over previous
//
#include <hip/hip_runtime.h>
#include <hip/hip_bf16.h>

#define DEVI __device__ __forceinline__

typedef __bf16 bf16x8 __attribute__((ext_vector_type(8)));
typedef float f32x4 __attribute__((ext_vector_type(4)));

DEVI unsigned short f2bf(float x) {
    union { __hip_bfloat16 h; unsigned short u; } v;
    v.h = __float2bfloat16(x);
    return v.u;
}

DEVI float exp2_fast(float x) {
#if __has_builtin(__builtin_amdgcn_exp2f)
    return __builtin_amdgcn_exp2f(x);
#else
    return exp2f(x);
#endif
}

DEVI void gload16(const void* gsrc, void* lds) {
    __builtin_amdgcn_global_load_lds(
        (const __attribute__((address_space(1))) void*)gsrc,
        (__attribute__((address_space(3))) void*)lds,
        16, 0, 0);
}

#define BARRIER_MEM() asm volatile("s_barrier" ::: "memory")
#define WAITVM(n) asm volatile("s_waitcnt vmcnt(" #n ")" ::: "memory")
#define LGKM0() asm volatile("s_waitcnt lgkmcnt(0)" ::: "memory")

// ---------------- conversion / transpose kernels ----------------

__global__ __launch_bounds__(256) void convert_f32_bf16_vec(
    const float* __restrict__ in, unsigned short* __restrict__ out, int n4) {
    int i = blockIdx.x * 256 + threadIdx.x;
    if (i >= n4) return;
    float4 v = reinterpret_cast<const float4*>(in)[i];
    ushort4 o;
    o.x = f2bf(v.x); o.y = f2bf(v.y); o.z = f2bf(v.z); o.w = f2bf(v.w);
    reinterpret_cast<ushort4*>(out)[i] = o;
}

// dst[c][r] = bf16(src[r][c]) for Wq/Wk/Wv (1024x1024), selected by blockIdx.z
__global__ __launch_bounds__(256) void transpose_wqkv(
    const float* __restrict__ wq, const float* __restrict__ wk,
    const float* __restrict__ wv, unsigned short* __restrict__ dst) {
    __shared__ unsigned short tile[32][33];
    const float* src = (blockIdx.z == 0) ? wq : (blockIdx.z == 1) ? wk : wv;
    unsigned short* d = dst + blockIdx.z * 1024 * 1024;
    int c0 = blockIdx.x * 32, r0 = blockIdx.y * 32;
    int tx = threadIdx.x & 31, ty = threadIdx.x >> 5;
    #pragma unroll
    for (int i = ty; i < 32; i += 8)
        tile[tx][i] = f2bf(src[(r0 + i) * 1024 + c0 + tx]);
    __syncthreads();
    #pragma unroll
    for (int i = ty; i < 32; i += 8)
        d[(c0 + i) * 1024 + r0 + tx] = tile[i][tx];
}

// dst[c][r] = bf16(src[r][c]); src is [R][Cc] fp32. grid (Cc/32, R/32), 256 thr.
__global__ __launch_bounds__(256) void transpose_f32_to_bf16t(
    const float* __restrict__ src, unsigned short* __restrict__ dst,
    int R, int Cc) {
    __shared__ unsigned short tile[32][33];
    int c0 = blockIdx.x * 32, r0 = blockIdx.y * 32;
    int tx = threadIdx.x & 31, ty = threadIdx.x >> 5;
    #pragma unroll
    for (int i = ty; i < 32; i += 8)
        tile[tx][i] = f2bf(src[(r0 + i) * Cc + c0 + tx]);
    __syncthreads();
    #pragma unroll
    for (int i = ty; i < 32; i += 8)
        dst[(c0 + i) * R + r0 + tx] = tile[i][tx];
}

// ---------------- gemm256 v3: 128x192 tile, BK=64, single-barrier K-loop ----
// C[8192,3072] = A[8192,1024] * Bt[3072,1024]^T. Same sync ledger, row
// geometry (128B rows) and XOR swizzle as the always-passing v2; only the
// tile split and work mapping change:
//  - LDS 80 KiB (2 x (128+192) x 64 bf16) -> 2 blocks/CU = 16 waves/CU
//    (v2 was 112 KiB -> 1 block/CU; all pipes idled at barriers).
//  - 1024 blocks = exactly 2 dispatch rounds at 2/CU.
//  - XCD mapping: XCD x owns M-panels [8x,8x+8) for BOTH halves (A L2-warm),
//    N split into two 8-tile halves -> concurrent set 5MB/XCD (was 7MB).
// 8 waves (2M x 4N), per-wave 64x48 = acc[4][3], 24 MFMA per K-tile.
__global__ __launch_bounds__(512, 2) void gemm256(
    const unsigned short* __restrict__ A, const unsigned short* __restrict__ Bt,
    unsigned short* __restrict__ q_out, unsigned short* __restrict__ k_out,
    unsigned short* __restrict__ v_out) {
    __shared__ unsigned short Ab[2][128 * 64];
    __shared__ unsigned short Bb[2][192 * 64];

    // bid -> (x = XCD, j): panel = x*8 + j[5:3], ntile = j[6]*8 + j[2:0]
    const int x = blockIdx.x & 7;
    const int j = blockIdx.x >> 3;            // 0..127
    const int bm = (x * 8 + ((j >> 3) & 7)) << 7;   // 64 M-panels of 128
    const int bn = (((j >> 6) << 3) | (j & 7)) * 192; // 16 N-tiles of 192

    const int tid = threadIdx.x;
    const int w = tid >> 6, l = tid & 63;
    const int wm = w >> 2, wn = w & 3;   // 2M x 4N
    const int lc = l & 15, lg = l >> 4;
    const int lr8 = l >> 3;
    const int colsw = 8 * ((l & 7) ^ lr8);   // inverse-swizzled src chunk

    const unsigned short* gA = A + (size_t)(bm + lr8) * 1024 + colsw;
    const unsigned short* gB = Bt + (size_t)(bn + lr8) * 1024 + colsw;

    const int p16_0 = (lg ^ (lc & 7)) * 16;
    const int p16_1 = ((4 | lg) ^ (lc & 7)) * 16;

    // A: 2 sweeps of 64 rows; B: 3 sweeps. 5 gload16/thread/tile.
    auto STAGE = [&](int bufn, int tt) {
        #pragma unroll
        for (int jj = 0; jj < 2; ++jj) {
            const int r0 = jj * 64 + w * 8;
            gload16(gA + (size_t)r0 * 1024 + tt * 64,
                    (char*)&Ab[bufn][0] + r0 * 128);
        }
        #pragma unroll
        for (int jj = 0; jj < 3; ++jj) {
            const int r0 = jj * 64 + w * 8;
            gload16(gB + (size_t)r0 * 1024 + tt * 64,
                    (char*)&Bb[bufn][0] + r0 * 128);
        }
    };

    bf16x8 a[4][2], b[3][2];
    f32x4 acc[4][3] = {};
    const int nt = 16;   // K = 1024 / 64

    STAGE(0, 0);

    #pragma unroll 1
    for (int t = 0; t < nt; ++t) {
        const int buf = t & 1;
        WAITVM(0);
        LGKM0();
        BARRIER_MEM();
        if (t + 1 < nt) STAGE(buf ^ 1, t + 1);

        const char* Arow = (const char*)&Ab[buf][0] + (wm * 64 + lc) * 128;
        const char* Brow = (const char*)&Bb[buf][0] + (wn * 48 + lc) * 128;
        #pragma unroll
        for (int fi = 0; fi < 4; ++fi) {
            a[fi][0] = *(const bf16x8*)(Arow + fi * 16 * 128 + p16_0);
            a[fi][1] = *(const bf16x8*)(Arow + fi * 16 * 128 + p16_1);
        }
        #pragma unroll
        for (int ni = 0; ni < 3; ++ni) {
            b[ni][0] = *(const bf16x8*)(Brow + ni * 16 * 128 + p16_0);
            b[ni][1] = *(const bf16x8*)(Brow + ni * 16 * 128 + p16_1);
        }
        __builtin_amdgcn_s_setprio(1);
        #pragma unroll
        for (int fi = 0; fi < 4; ++fi)
            #pragma unroll
            for (int ni = 0; ni < 3; ++ni) {
                acc[fi][ni] = __builtin_amdgcn_mfma_f32_16x16x32_bf16(
                    a[fi][0], b[ni][0], acc[fi][ni], 0, 0, 0);
                acc[fi][ni] = __builtin_amdgcn_mfma_f32_16x16x32_bf16(
                    a[fi][1], b[ni][1], acc[fi][ni], 0, 0, 0);
            }
        __builtin_amdgcn_s_setprio(0);
    }

    // epilogue: per-ni column range (16 wide, never straddles 1024 boundary)
    #pragma unroll
    for (int ni = 0; ni < 3; ++ni) {
        const int n = bn + wn * 48 + ni * 16 + lc;
        const int which = n >> 10;
        const int rr = n & 1023;
        if (which == 2) {
            // V third: store directly transposed into v_t [bh][64][2048]
            #pragma unroll
            for (int fi = 0; fi < 4; ++fi) {
                const int m = bm + wm * 64 + fi * 16 + lg * 4;
                const int bhh = (m >> 11) * 16 + (rr >> 6);
                const int d = rr & 63;
                const int tt = m & 2047;
                ushort4 o;
                o.x = f2bf(acc[fi][ni][0]); o.y = f2bf(acc[fi][ni][1]);
                o.z = f2bf(acc[fi][ni][2]); o.w = f2bf(acc[fi][ni][3]);
                *reinterpret_cast<ushort4*>(
                    &v_out[((size_t)bhh * 64 + d) * 2048 + tt]) = o;
            }
        } else {
            unsigned short* dst = which ? k_out : q_out;
            #pragma unroll
            for (int fi = 0; fi < 4; ++fi)
                #pragma unroll
                for (int r = 0; r < 4; ++r) {
                    const int m = bm + wm * 64 + fi * 16 + lg * 4 + r;
                    dst[(size_t)m * 1024 + rr] = f2bf(acc[fi][ni][r]);
                }
        }
    }
}

// ---------------- GEMM: C[M,N] = A[M,K] * Bt[N,K]^T (bf16 in, fp32 acc) ------
// (kept for the small output projection, K=64)
template <int EPI>
__global__ __launch_bounds__(256) void gemm_bt(
    const unsigned short* __restrict__ A, const unsigned short* __restrict__ Bt,
    int Mdim, int Ndim, int Kdim,
    unsigned short* __restrict__ q_out, unsigned short* __restrict__ k_out,
    unsigned short* __restrict__ v_out, float* __restrict__ c_out) {
    __shared__ unsigned short As[128 * 32];
    __shared__ unsigned short Bs[128 * 32];
    const int ntn = Ndim >> 7;
    const int bm = (blockIdx.x / ntn) << 7;
    const int bn = (blockIdx.x % ntn) << 7;
    const int tid = threadIdx.x;
    const int w = tid >> 6, l = tid & 63;
    const int wr = w >> 1, wc = w & 1;
    const int lrow = l >> 2, lcb = (l & 3) * 8;
    const int lc = l & 15, lg = l >> 4;

    f32x4 acc[4][4] = {};

    for (int k0 = 0; k0 < Kdim; k0 += 32) {
        __syncthreads();
        #pragma unroll
        for (int i = 0; i < 2; ++i) {
            int j = w * 2 + i;
            gload16(A + (bm + j * 16 + lrow) * Kdim + k0 + lcb, (char*)As + j * 1024);
            gload16(Bt + (bn + j * 16 + lrow) * Kdim + k0 + lcb, (char*)Bs + j * 1024);
        }
        __syncthreads();
        bf16x8 af[4], bfr[4];
        #pragma unroll
        for (int mi = 0; mi < 4; ++mi)
            af[mi] = *reinterpret_cast<const bf16x8*>(&As[(wr * 64 + mi * 16 + lc) * 32 + lg * 8]);
        #pragma unroll
        for (int ni = 0; ni < 4; ++ni)
            bfr[ni] = *reinterpret_cast<const bf16x8*>(&Bs[(wc * 64 + ni * 16 + lc) * 32 + lg * 8]);
        #pragma unroll
        for (int mi = 0; mi < 4; ++mi)
            #pragma unroll
            for (int ni = 0; ni < 4; ++ni)
                acc[mi][ni] = __builtin_amdgcn_mfma_f32_16x16x32_bf16(
                    af[mi], bfr[ni], acc[mi][ni], 0, 0, 0);
    }

    #pragma unroll
    for (int mi = 0; mi < 4; ++mi) {
        #pragma unroll
        for (int ni = 0; ni < 4; ++ni) {
            #pragma unroll
            for (int r = 0; r < 4; ++r) {
                int m = bm + wr * 64 + mi * 16 + lg * 4 + r;
                int n = bn + wc * 64 + ni * 16 + lc;
                float val = acc[mi][ni][r];
                if (EPI == 0) {
                    int which = n >> 10, rr = n & 1023;
                    unsigned short* dst = (which == 0) ? q_out : (which == 1) ? k_out : v_out;
                    dst[m * 1024 + rr] = f2bf(val);
                } else {
                    c_out[m * Ndim + n] = val;
                }
            }
        }
    }
}

// ---------------- flash attention v6 ----------------------------------------
// FROZEN (byte-identical to the round-13 PASSING kernel). The r9-r12 NaN
// streak came from perturbations of this kernel's staging schedule; no
// further edits to its sync structure.
__global__ __launch_bounds__(512, 4) void attn_kernel(
    const unsigned short* __restrict__ qb, const unsigned short* __restrict__ kb,
    const unsigned short* __restrict__ vt, unsigned short* __restrict__ ypart) {
    __shared__ unsigned short Ks[3][64 * 64];
    __shared__ unsigned short Vs[3][64 * 64];
    __shared__ unsigned short plds[8][16 * 72];

    const int i = blockIdx.x;
    const int slot = i >> 3;
    const int bh = (i & 7) + ((slot >> 3) << 3);
    const int pr = slot & 7;
    const int b = bh >> 4, h = bh & 15;
    const int tid = threadIdx.x, w = tid >> 6, l = tid & 63;
    const int lc = l & 15, lg = l >> 4;

    const float SCL = 0.125f * 1.44269504f;  // 1/sqrt(64) * log2(e)

    const int rowc = l >> 3;
    const int colsw = 8 * ((l & 7) ^ rowc);
    const unsigned short* kbh = kb + (b * 2048) * 1024 + h * 64;
    const unsigned short* vbh = vt + bh * 64 * 2048;
    const int swz = (lc & 7) * 8;

    unsigned short* pl = &plds[w][0];

    auto STAGE = [&](int bufn, int kt) {
        const int tk0s = kt << 6;
        const int row = w * 8 + rowc;
        gload16(kbh + (tk0s + row) * 1024 + colsw, (char*)&Ks[bufn][0] + w * 1024);
        gload16(vbh + row * 2048 + tk0s + colsw, (char*)&Vs[bufn][0] + w * 1024);
    };

    auto run_pass = [&](int qblk) {
        const int q0 = qblk << 7;
        const int qrowW = q0 + w * 16;       // wave's 16 q-rows

        bf16x8 qf[2];
        {
            const unsigned short* qp =
                qb + (b * 2048 + qrowW + lc) * 1024 + h * 64;
            qf[0] = *reinterpret_cast<const bf16x8*>(qp + lg * 8);
            qf[1] = *reinterpret_cast<const bf16x8*>(qp + 32 + lg * 8);
        }

        f32x4 accO[4] = {};
        float lsum = 0.f;

        const int nkt = 2 * qblk + 2;
        STAGE(0, 0);
        STAGE(1, 1);
        int cur = 0;

        for (int kt = 0; kt < nkt; ++kt) {
            const int tk0 = kt << 6;
            if (kt + 1 < nkt) { WAITVM(2); } else { WAITVM(0); }
            BARRIER_MEM();      // all waves done computing tile kt-1; tile kt staged
            if (kt + 2 < nkt) {
                const int sb = (cur >= 1) ? cur - 1 : cur + 2;  // (kt+2)%3
                STAGE(sb, kt + 2);
            }

            if (tk0 <= qrowW + 15) {
                // ---- QK^T (swapped): s[ni] = S^T[k=tk0+16ni+4lg+r][q=qrowW+lc]
                f32x4 s[4] = {};
                #pragma unroll
                for (int ni = 0; ni < 4; ++ni) {
                    const unsigned short* kr = &Ks[cur][(ni * 16 + lc) * 64];
                    bf16x8 kf0 = *reinterpret_cast<const bf16x8*>(&kr[(lg * 8) ^ swz]);
                    bf16x8 kf1 = *reinterpret_cast<const bf16x8*>(&kr[(32 + lg * 8) ^ swz]);
                    s[ni] = __builtin_amdgcn_mfma_f32_16x16x32_bf16(kf0, qf[0], s[ni], 0, 0, 0);
                    s[ni] = __builtin_amdgcn_mfma_f32_16x16x32_bf16(kf1, qf[1], s[ni], 0, 0, 0);
                }
                // ---- scale + mask + exp + pack + P^T->LDS (4x b64) ----
                const bool needmask = (tk0 + 63 > qrowW);
                const int tq = qrowW + lc;
                #pragma unroll
                for (int ni = 0; ni < 4; ++ni) {
                    float pv[4];
                    #pragma unroll
                    for (int r = 0; r < 4; ++r) {
                        float sv = s[ni][r] * SCL;
                        if (needmask) {
                            int tk = tk0 + ni * 16 + lg * 4 + r;
                            sv = (tk > tq) ? -INFINITY : sv;
                        }
                        pv[r] = exp2_fast(sv);
                        lsum += pv[r];
                    }
                    unsigned int w0, w1;
                    asm("v_cvt_pk_bf16_f32 %0, %1, %2" : "=v"(w0) : "v"(pv[0]), "v"(pv[1]));
                    asm("v_cvt_pk_bf16_f32 %0, %1, %2" : "=v"(w1) : "v"(pv[2]), "v"(pv[3]));
                    uint2 pk2; pk2.x = w0; pk2.y = w1;
                    *reinterpret_cast<uint2*>(&pl[lc * 72 + ni * 16 + lg * 4]) = pk2;
                }
                // ---- P@V (swapped): accO[ni] = O^T[d=16ni+4lg+r][q=qrowW+lc]
                bf16x8 pf0 = *reinterpret_cast<const bf16x8*>(&pl[lc * 72 + lg * 8]);
                bf16x8 pf1 = *reinterpret_cast<const bf16x8*>(&pl[lc * 72 + 32 + lg * 8]);
                #pragma unroll
                for (int ni = 0; ni < 4; ++ni) {
                    const unsigned short* vr = &Vs[cur][(ni * 16 + lc) * 64];
                    bf16x8 vf0 = *reinterpret_cast<const bf16x8*>(&vr[(lg * 8) ^ swz]);
                    bf16x8 vf1 = *reinterpret_cast<const bf16x8*>(&vr[(32 + lg * 8) ^ swz]);
                    accO[ni] = __builtin_amdgcn_mfma_f32_16x16x32_bf16(vf0, pf0, accO[ni], 0, 0, 0);
                    accO[ni] = __builtin_amdgcn_mfma_f32_16x16x32_bf16(vf1, pf1, accO[ni], 0, 0, 0);
                }
            }
            cur = (cur + 1 == 3) ? 0 : cur + 1;
        }
        BARRIER_MEM();   // protect pass-2 re-staging of bufs 0/1

        // row-sum reduce (2 shuffles), then vectorized scaled store
        float tsum = lsum;
        tsum += __shfl_xor(tsum, 16);
        tsum += __shfl_xor(tsum, 32);
        const float rinv = 1.0f / tsum;
        const int tq = qrowW + lc;
        #pragma unroll
        for (int ni = 0; ni < 4; ++ni) {
            ushort4 o;
            o.x = f2bf(accO[ni][0] * rinv);
            o.y = f2bf(accO[ni][1] * rinv);
            o.z = f2bf(accO[ni][2] * rinv);
            o.w = f2bf(accO[ni][3] * rinv);
            *reinterpret_cast<ushort4*>(
                &ypart[(bh * 2048 + tq) * 64 + ni * 16 + lg * 4]) = o;
        }
    };

    run_pass(15 - pr);   // long pass first (primes L2 for the short pass)
    run_pass(pr);
}

// ---------------- head-sum reduce: y[m][d] = sum_h ypart[b][h][t][d] --------
__global__ __launch_bounds__(256) void reduce_heads(
    const unsigned short* __restrict__ ypart, unsigned short* __restrict__ yb) {
    int idx = blockIdx.x * 256 + threadIdx.x;  // < 8192*64
    int d = idx & 63, m = idx >> 6;
    int b = m >> 11, t = m & 2047;
    const unsigned short* p = ypart + ((b * 16) * 2048 + t) * 64 + d;
    float s = 0.f;
    #pragma unroll
    for (int h = 0; h < 16; ++h) {
        union { unsigned short u; __hip_bfloat16 h; } v;
        v.u = p[h * 2048 * 64];
        s += __bfloat162float(v.h);
    }
    yb[idx] = f2bf(s);
}

// ---------------- launcher ----------------

extern "C" void kernel_launch(void* const* d_in, const int* in_sizes, int n_in,
                              void* d_out, int out_size, void* d_ws, size_t ws_size,
                              hipStream_t stream) {
    const float* x  = (const float*)d_in[0];
    const float* Wq = (const float*)d_in[1];
    const float* Wk = (const float*)d_in[2];
    const float* Wv = (const float*)d_in[3];
    const float* Wp = (const float*)d_in[4];
    float* out = (float*)d_out;

    // workspace layout (bytes):
    //   [0, 16777216)      ypart bf16 [64][2048][64]  (aliases xb, phase 4+)
    //   [0, 16777216)      xb bf16 [8192][1024]       (phase 1 only)
    //   [33554432,39845888) wqkv_t bf16 [3072][1024]
    //   [39845888,39976960) wp_t bf16 [1024][64]
    //   [39976960,56754176) q_proj bf16
    //   [56754176,73531392) k_proj bf16
    //   [73531392,90308608) v_t bf16 [64][64][2048]   (written by gemm256)
    //   [90308608,91357184) y_b bf16 [8192][64]
    if (ws_size < 91357184) return;
    char* ws = (char*)d_ws;
    unsigned short* ypart = (unsigned short*)ws;
    unsigned short* xb   = (unsigned short*)ws;
    unsigned short* wt   = (unsigned short*)(ws + 33554432);
    unsigned short* wpt  = (unsigned short*)(ws + 39845888);
    unsigned short* qbf  = (unsigned short*)(ws + 39976960);
    unsigned short* kbf  = (unsigned short*)(ws + 56754176);
    unsigned short* vtb  = (unsigned short*)(ws + 73531392);
    unsigned short* yb   = (unsigned short*)(ws + 90308608);

    convert_f32_bf16_vec<<<8192, 256, 0, stream>>>(x, xb, 2097152);
    transpose_wqkv<<<dim3(32, 32, 3), 256, 0, stream>>>(Wq, Wk, Wv, wt);
    transpose_f32_to_bf16t<<<dim3(32, 2), 256, 0, stream>>>(Wp, wpt, 64, 1024);

    gemm256<<<1024, 512, 0, stream>>>(xb, wt, qbf, kbf, vtb);

    attn_kernel<<<512, 512, 0, stream>>>(qbf, kbf, vtb, ypart);

    reduce_heads<<<2048, 256, 0, stream>>>(ypart, yb);

    gemm_bt<1><<<(8192 / 128) * (1024 / 128), 256, 0, stream>>>(
        yb, wpt, 8192, 1024, 64, nullptr, nullptr, nullptr, out);
}

// Round 15
// 148.543 us; speedup vs baseline: 1.0455x; 1.0068x over previous
//
#include <hip/hip_runtime.h>
#include <hip/hip_bf16.h>

#define DEVI __device__ __forceinline__

typedef __bf16 bf16x8 __attribute__((ext_vector_type(8)));
typedef float f32x4 __attribute__((ext_vector_type(4)));

DEVI unsigned short f2bf(float x) {
    union { __hip_bfloat16 h; unsigned short u; } v;
    v.h = __float2bfloat16(x);
    return v.u;
}

DEVI float bf2f(unsigned short u) {
    union { unsigned short u; __hip_bfloat16 h; } v;
    v.u = u;
    return __bfloat162float(v.h);
}

DEVI float exp2_fast(float x) {
#if __has_builtin(__builtin_amdgcn_exp2f)
    return __builtin_amdgcn_exp2f(x);
#else
    return exp2f(x);
#endif
}

DEVI void gload16(const void* gsrc, void* lds) {
    __builtin_amdgcn_global_load_lds(
        (const __attribute__((address_space(1))) void*)gsrc,
        (__attribute__((address_space(3))) void*)lds,
        16, 0, 0);
}

#define BARRIER_MEM() asm volatile("s_barrier" ::: "memory")
#define WAITVM(n) asm volatile("s_waitcnt vmcnt(" #n ")" ::: "memory")
#define LGKM0() asm volatile("s_waitcnt lgkmcnt(0)" ::: "memory")

// ---------------- conversion / transpose kernels ----------------

__global__ __launch_bounds__(256) void convert_f32_bf16_vec(
    const float* __restrict__ in, unsigned short* __restrict__ out, int n4) {
    int i = blockIdx.x * 256 + threadIdx.x;
    if (i >= n4) return;
    float4 v = reinterpret_cast<const float4*>(in)[i];
    ushort4 o;
    o.x = f2bf(v.x); o.y = f2bf(v.y); o.z = f2bf(v.z); o.w = f2bf(v.w);
    reinterpret_cast<ushort4*>(out)[i] = o;
}

// z=0..2: Wq/Wk/Wv (1024x1024) -> wqkv_t; z=3: Wp (64x1024) -> wp_t
__global__ __launch_bounds__(256) void transpose_wqkvp(
    const float* __restrict__ wq, const float* __restrict__ wk,
    const float* __restrict__ wv, const float* __restrict__ wp,
    unsigned short* __restrict__ dst, unsigned short* __restrict__ wpt) {
    __shared__ unsigned short tile[32][33];
    const int z = blockIdx.z;
    if (z == 3 && blockIdx.y >= 2) return;
    const float* src = (z == 0) ? wq : (z == 1) ? wk : (z == 2) ? wv : wp;
    const int R = (z == 3) ? 64 : 1024;
    unsigned short* d = (z == 3) ? wpt : dst + z * 1024 * 1024;
    int c0 = blockIdx.x * 32, r0 = blockIdx.y * 32;
    int tx = threadIdx.x & 31, ty = threadIdx.x >> 5;
    #pragma unroll
    for (int i = ty; i < 32; i += 8)
        tile[tx][i] = f2bf(src[(r0 + i) * 1024 + c0 + tx]);
    __syncthreads();
    #pragma unroll
    for (int i = ty; i < 32; i += 8)
        d[(c0 + i) * R + r0 + tx] = tile[i][tx];
}

// ---------------- gemm256 v3: 128x192 tile, BK=64, single-barrier K-loop ----
// (byte-identical to the round-14 PASSING version)
__global__ __launch_bounds__(512, 2) void gemm256(
    const unsigned short* __restrict__ A, const unsigned short* __restrict__ Bt,
    unsigned short* __restrict__ q_out, unsigned short* __restrict__ k_out,
    unsigned short* __restrict__ v_out) {
    __shared__ unsigned short Ab[2][128 * 64];
    __shared__ unsigned short Bb[2][192 * 64];

    // bid -> (x = XCD, j): panel = x*8 + j[5:3], ntile = j[6]*8 + j[2:0]
    const int x = blockIdx.x & 7;
    const int j = blockIdx.x >> 3;            // 0..127
    const int bm = (x * 8 + ((j >> 3) & 7)) << 7;   // 64 M-panels of 128
    const int bn = (((j >> 6) << 3) | (j & 7)) * 192; // 16 N-tiles of 192

    const int tid = threadIdx.x;
    const int w = tid >> 6, l = tid & 63;
    const int wm = w >> 2, wn = w & 3;   // 2M x 4N
    const int lc = l & 15, lg = l >> 4;
    const int lr8 = l >> 3;
    const int colsw = 8 * ((l & 7) ^ lr8);   // inverse-swizzled src chunk

    const unsigned short* gA = A + (size_t)(bm + lr8) * 1024 + colsw;
    const unsigned short* gB = Bt + (size_t)(bn + lr8) * 1024 + colsw;

    const int p16_0 = (lg ^ (lc & 7)) * 16;
    const int p16_1 = ((4 | lg) ^ (lc & 7)) * 16;

    // A: 2 sweeps of 64 rows; B: 3 sweeps. 5 gload16/thread/tile.
    auto STAGE = [&](int bufn, int tt) {
        #pragma unroll
        for (int jj = 0; jj < 2; ++jj) {
            const int r0 = jj * 64 + w * 8;
            gload16(gA + (size_t)r0 * 1024 + tt * 64,
                    (char*)&Ab[bufn][0] + r0 * 128);
        }
        #pragma unroll
        for (int jj = 0; jj < 3; ++jj) {
            const int r0 = jj * 64 + w * 8;
            gload16(gB + (size_t)r0 * 1024 + tt * 64,
                    (char*)&Bb[bufn][0] + r0 * 128);
        }
    };

    bf16x8 a[4][2], b[3][2];
    f32x4 acc[4][3] = {};
    const int nt = 16;   // K = 1024 / 64

    STAGE(0, 0);

    #pragma unroll 1
    for (int t = 0; t < nt; ++t) {
        const int buf = t & 1;
        WAITVM(0);
        LGKM0();
        BARRIER_MEM();
        if (t + 1 < nt) STAGE(buf ^ 1, t + 1);

        const char* Arow = (const char*)&Ab[buf][0] + (wm * 64 + lc) * 128;
        const char* Brow = (const char*)&Bb[buf][0] + (wn * 48 + lc) * 128;
        #pragma unroll
        for (int fi = 0; fi < 4; ++fi) {
            a[fi][0] = *(const bf16x8*)(Arow + fi * 16 * 128 + p16_0);
            a[fi][1] = *(const bf16x8*)(Arow + fi * 16 * 128 + p16_1);
        }
        #pragma unroll
        for (int ni = 0; ni < 3; ++ni) {
            b[ni][0] = *(const bf16x8*)(Brow + ni * 16 * 128 + p16_0);
            b[ni][1] = *(const bf16x8*)(Brow + ni * 16 * 128 + p16_1);
        }
        __builtin_amdgcn_s_setprio(1);
        #pragma unroll
        for (int fi = 0; fi < 4; ++fi)
            #pragma unroll
            for (int ni = 0; ni < 3; ++ni) {
                acc[fi][ni] = __builtin_amdgcn_mfma_f32_16x16x32_bf16(
                    a[fi][0], b[ni][0], acc[fi][ni], 0, 0, 0);
                acc[fi][ni] = __builtin_amdgcn_mfma_f32_16x16x32_bf16(
                    a[fi][1], b[ni][1], acc[fi][ni], 0, 0, 0);
            }
        __builtin_amdgcn_s_setprio(0);
    }

    // epilogue: per-ni column range (16 wide, never straddles 1024 boundary)
    #pragma unroll
    for (int ni = 0; ni < 3; ++ni) {
        const int n = bn + wn * 48 + ni * 16 + lc;
        const int which = n >> 10;
        const int rr = n & 1023;
        if (which == 2) {
            // V third: store directly transposed into v_t [bh][64][2048]
            #pragma unroll
            for (int fi = 0; fi < 4; ++fi) {
                const int m = bm + wm * 64 + fi * 16 + lg * 4;
                const int bhh = (m >> 11) * 16 + (rr >> 6);
                const int d = rr & 63;
                const int tt = m & 2047;
                ushort4 o;
                o.x = f2bf(acc[fi][ni][0]); o.y = f2bf(acc[fi][ni][1]);
                o.z = f2bf(acc[fi][ni][2]); o.w = f2bf(acc[fi][ni][3]);
                *reinterpret_cast<ushort4*>(
                    &v_out[((size_t)bhh * 64 + d) * 2048 + tt]) = o;
            }
        } else {
            unsigned short* dst = which ? k_out : q_out;
            #pragma unroll
            for (int fi = 0; fi < 4; ++fi)
                #pragma unroll
                for (int r = 0; r < 4; ++r) {
                    const int m = bm + wm * 64 + fi * 16 + lg * 4 + r;
                    dst[(size_t)m * 1024 + rr] = f2bf(acc[fi][ni][r]);
                }
        }
    }
}

// ---------------- fused head-sum + output projection ------------------------
// out[M=8192, N=1024] = (sum_h ypart[b][h][t][:]) @ WpT^T, fp32 out.
// 512 blocks (64 M-panels x 8 N-tiles), 256 thr (4 waves, 2Mx2N), K=64.
// A: head-sum of ypart computed in-kernel into padded LDS (stride 72 elems,
// bank-conflict-free); B: wpt staged via the PROVEN gemm256 gload16 +
// XOR-swizzle pattern (128B rows). Single __syncthreads (compiler drains
// vmcnt+lgkm). XCD mapping: XCD x owns M-panels [8x,8x+8) -> each panel's
// ypart slice (256KB) stays L2-resident across its 8 N-blocks.
__global__ __launch_bounds__(256) void gemm_out_fused(
    const unsigned short* __restrict__ ypart,   // [64][2048][64] bf16
    const unsigned short* __restrict__ wpt,     // [1024][64] bf16 (Wp^T)
    float* __restrict__ out) {                  // [8192][1024] fp32
    __shared__ unsigned short As[128 * 72];
    __shared__ unsigned short Bs[128 * 64];

    const int x = blockIdx.x & 7;
    const int j = blockIdx.x >> 3;            // 0..63
    const int bm = (x * 8 + (j & 7)) << 7;    // 64 M-panels of 128
    const int bn = (j >> 3) << 7;             // 8 N-tiles of 128

    const int tid = threadIdx.x;
    const int w = tid >> 6, l = tid & 63;
    const int wr = w >> 1, wc = w & 1;
    const int lc = l & 15, lg = l >> 4;
    const int lr8 = l >> 3;
    const int colsw = 8 * ((l & 7) ^ lr8);

    // stage B^T tile (rows bn..bn+127 of wpt), inverse-swizzled source
    const unsigned short* gB = wpt + (size_t)(bn + lr8) * 64 + colsw;
    #pragma unroll
    for (int jj = 0; jj < 4; ++jj) {
        const int r0 = jj * 32 + w * 8;
        gload16(gB + (size_t)r0 * 64, (char*)Bs + r0 * 128);
    }

    // head-summed A rows bm..bm+127 (panel never straddles b)
    const int b = bm >> 11, t0 = bm & 2047;
    const unsigned short* yb0 = ypart + ((size_t)(b * 16) * 2048 + t0) * 64;
    #pragma unroll
    for (int it = 0; it < 8; ++it) {
        const int idx = it * 256 + tid;       // 0..2047
        const int row = idx >> 4;             // 0..127
        const int d4 = (idx & 15) * 4;        // 0..60
        float s0 = 0.f, s1 = 0.f, s2 = 0.f, s3 = 0.f;
        #pragma unroll
        for (int h = 0; h < 16; ++h) {
            ushort4 v = *reinterpret_cast<const ushort4*>(
                yb0 + ((size_t)h * 2048 + row) * 64 + d4);
            s0 += bf2f(v.x); s1 += bf2f(v.y);
            s2 += bf2f(v.z); s3 += bf2f(v.w);
        }
        ushort4 o;
        o.x = f2bf(s0); o.y = f2bf(s1); o.z = f2bf(s2); o.w = f2bf(s3);
        *reinterpret_cast<ushort4*>(&As[row * 72 + d4]) = o;
    }

    __syncthreads();   // full vmcnt+lgkm drain (gload_lds + ds_write)

    const int p16_0 = (lg ^ (lc & 7)) * 16;
    const int p16_1 = ((4 | lg) ^ (lc & 7)) * 16;

    f32x4 acc[4][4] = {};
    #pragma unroll
    for (int half = 0; half < 2; ++half) {
        const int p16 = half ? p16_1 : p16_0;
        bf16x8 af[4], bfr[4];
        #pragma unroll
        for (int mi = 0; mi < 4; ++mi)
            af[mi] = *reinterpret_cast<const bf16x8*>(
                &As[(wr * 64 + mi * 16 + lc) * 72 + half * 32 + lg * 8]);
        #pragma unroll
        for (int ni = 0; ni < 4; ++ni)
            bfr[ni] = *reinterpret_cast<const bf16x8*>(
                (const char*)Bs + (wc * 64 + ni * 16 + lc) * 128 + p16);
        #pragma unroll
        for (int mi = 0; mi < 4; ++mi)
            #pragma unroll
            for (int ni = 0; ni < 4; ++ni)
                acc[mi][ni] = __builtin_amdgcn_mfma_f32_16x16x32_bf16(
                    af[mi], bfr[ni], acc[mi][ni], 0, 0, 0);
    }

    #pragma unroll
    for (int mi = 0; mi < 4; ++mi)
        #pragma unroll
        for (int ni = 0; ni < 4; ++ni)
            #pragma unroll
            for (int r = 0; r < 4; ++r) {
                const int m = bm + wr * 64 + mi * 16 + lg * 4 + r;
                const int n = bn + wc * 64 + ni * 16 + lc;
                out[(size_t)m * 1024 + n] = acc[mi][ni][r];
            }
}

// ---------------- flash attention v6 ----------------------------------------
// FROZEN (byte-identical to the round-13/14 PASSING kernel). The r9-r12 NaN
// streak came from perturbations of this kernel; no edits.
__global__ __launch_bounds__(512, 4) void attn_kernel(
    const unsigned short* __restrict__ qb, const unsigned short* __restrict__ kb,
    const unsigned short* __restrict__ vt, unsigned short* __restrict__ ypart) {
    __shared__ unsigned short Ks[3][64 * 64];
    __shared__ unsigned short Vs[3][64 * 64];
    __shared__ unsigned short plds[8][16 * 72];

    const int i = blockIdx.x;
    const int slot = i >> 3;
    const int bh = (i & 7) + ((slot >> 3) << 3);
    const int pr = slot & 7;
    const int b = bh >> 4, h = bh & 15;
    const int tid = threadIdx.x, w = tid >> 6, l = tid & 63;
    const int lc = l & 15, lg = l >> 4;

    const float SCL = 0.125f * 1.44269504f;  // 1/sqrt(64) * log2(e)

    const int rowc = l >> 3;
    const int colsw = 8 * ((l & 7) ^ rowc);
    const unsigned short* kbh = kb + (b * 2048) * 1024 + h * 64;
    const unsigned short* vbh = vt + bh * 64 * 2048;
    const int swz = (lc & 7) * 8;

    unsigned short* pl = &plds[w][0];

    auto STAGE = [&](int bufn, int kt) {
        const int tk0s = kt << 6;
        const int row = w * 8 + rowc;
        gload16(kbh + (tk0s + row) * 1024 + colsw, (char*)&Ks[bufn][0] + w * 1024);
        gload16(vbh + row * 2048 + tk0s + colsw, (char*)&Vs[bufn][0] + w * 1024);
    };

    auto run_pass = [&](int qblk) {
        const int q0 = qblk << 7;
        const int qrowW = q0 + w * 16;       // wave's 16 q-rows

        bf16x8 qf[2];
        {
            const unsigned short* qp =
                qb + (b * 2048 + qrowW + lc) * 1024 + h * 64;
            qf[0] = *reinterpret_cast<const bf16x8*>(qp + lg * 8);
            qf[1] = *reinterpret_cast<const bf16x8*>(qp + 32 + lg * 8);
        }

        f32x4 accO[4] = {};
        float lsum = 0.f;

        const int nkt = 2 * qblk + 2;
        STAGE(0, 0);
        STAGE(1, 1);
        int cur = 0;

        for (int kt = 0; kt < nkt; ++kt) {
            const int tk0 = kt << 6;
            if (kt + 1 < nkt) { WAITVM(2); } else { WAITVM(0); }
            BARRIER_MEM();      // all waves done computing tile kt-1; tile kt staged
            if (kt + 2 < nkt) {
                const int sb = (cur >= 1) ? cur - 1 : cur + 2;  // (kt+2)%3
                STAGE(sb, kt + 2);
            }

            if (tk0 <= qrowW + 15) {
                // ---- QK^T (swapped): s[ni] = S^T[k=tk0+16ni+4lg+r][q=qrowW+lc]
                f32x4 s[4] = {};
                #pragma unroll
                for (int ni = 0; ni < 4; ++ni) {
                    const unsigned short* kr = &Ks[cur][(ni * 16 + lc) * 64];
                    bf16x8 kf0 = *reinterpret_cast<const bf16x8*>(&kr[(lg * 8) ^ swz]);
                    bf16x8 kf1 = *reinterpret_cast<const bf16x8*>(&kr[(32 + lg * 8) ^ swz]);
                    s[ni] = __builtin_amdgcn_mfma_f32_16x16x32_bf16(kf0, qf[0], s[ni], 0, 0, 0);
                    s[ni] = __builtin_amdgcn_mfma_f32_16x16x32_bf16(kf1, qf[1], s[ni], 0, 0, 0);
                }
                // ---- scale + mask + exp + pack + P^T->LDS (4x b64) ----
                const bool needmask = (tk0 + 63 > qrowW);
                const int tq = qrowW + lc;
                #pragma unroll
                for (int ni = 0; ni < 4; ++ni) {
                    float pv[4];
                    #pragma unroll
                    for (int r = 0; r < 4; ++r) {
                        float sv = s[ni][r] * SCL;
                        if (needmask) {
                            int tk = tk0 + ni * 16 + lg * 4 + r;
                            sv = (tk > tq) ? -INFINITY : sv;
                        }
                        pv[r] = exp2_fast(sv);
                        lsum += pv[r];
                    }
                    unsigned int w0, w1;
                    asm("v_cvt_pk_bf16_f32 %0, %1, %2" : "=v"(w0) : "v"(pv[0]), "v"(pv[1]));
                    asm("v_cvt_pk_bf16_f32 %0, %1, %2" : "=v"(w1) : "v"(pv[2]), "v"(pv[3]));
                    uint2 pk2; pk2.x = w0; pk2.y = w1;
                    *reinterpret_cast<uint2*>(&pl[lc * 72 + ni * 16 + lg * 4]) = pk2;
                }
                // ---- P@V (swapped): accO[ni] = O^T[d=16ni+4lg+r][q=qrowW+lc]
                bf16x8 pf0 = *reinterpret_cast<const bf16x8*>(&pl[lc * 72 + lg * 8]);
                bf16x8 pf1 = *reinterpret_cast<const bf16x8*>(&pl[lc * 72 + 32 + lg * 8]);
                #pragma unroll
                for (int ni = 0; ni < 4; ++ni) {
                    const unsigned short* vr = &Vs[cur][(ni * 16 + lc) * 64];
                    bf16x8 vf0 = *reinterpret_cast<const bf16x8*>(&vr[(lg * 8) ^ swz]);
                    bf16x8 vf1 = *reinterpret_cast<const bf16x8*>(&vr[(32 + lg * 8) ^ swz]);
                    accO[ni] = __builtin_amdgcn_mfma_f32_16x16x32_bf16(vf0, pf0, accO[ni], 0, 0, 0);
                    accO[ni] = __builtin_amdgcn_mfma_f32_16x16x32_bf16(vf1, pf1, accO[ni], 0, 0, 0);
                }
            }
            cur = (cur + 1 == 3) ? 0 : cur + 1;
        }
        BARRIER_MEM();   // protect pass-2 re-staging of bufs 0/1

        // row-sum reduce (2 shuffles), then vectorized scaled store
        float tsum = lsum;
        tsum += __shfl_xor(tsum, 16);
        tsum += __shfl_xor(tsum, 32);
        const float rinv = 1.0f / tsum;
        const int tq = qrowW + lc;
        #pragma unroll
        for (int ni = 0; ni < 4; ++ni) {
            ushort4 o;
            o.x = f2bf(accO[ni][0] * rinv);
            o.y = f2bf(accO[ni][1] * rinv);
            o.z = f2bf(accO[ni][2] * rinv);
            o.w = f2bf(accO[ni][3] * rinv);
            *reinterpret_cast<ushort4*>(
                &ypart[(bh * 2048 + tq) * 64 + ni * 16 + lg * 4]) = o;
        }
    };

    run_pass(15 - pr);   // long pass first (primes L2 for the short pass)
    run_pass(pr);
}

// ---------------- launcher ----------------

extern "C" void kernel_launch(void* const* d_in, const int* in_sizes, int n_in,
                              void* d_out, int out_size, void* d_ws, size_t ws_size,
                              hipStream_t stream) {
    const float* x  = (const float*)d_in[0];
    const float* Wq = (const float*)d_in[1];
    const float* Wk = (const float*)d_in[2];
    const float* Wv = (const float*)d_in[3];
    const float* Wp = (const float*)d_in[4];
    float* out = (float*)d_out;

    // workspace layout (bytes):
    //   [0, 16777216)      ypart bf16 [64][2048][64]  (aliases xb, phase 4+)
    //   [0, 16777216)      xb bf16 [8192][1024]       (phase 1 only)
    //   [33554432,39845888) wqkv_t bf16 [3072][1024]
    //   [39845888,39976960) wp_t bf16 [1024][64]
    //   [39976960,56754176) q_proj bf16
    //   [56754176,73531392) k_proj bf16
    //   [73531392,90308608) v_t bf16 [64][64][2048]   (written by gemm256)
    if (ws_size < 91357184) return;
    char* ws = (char*)d_ws;
    unsigned short* ypart = (unsigned short*)ws;
    unsigned short* xb   = (unsigned short*)ws;
    unsigned short* wt   = (unsigned short*)(ws + 33554432);
    unsigned short* wpt  = (unsigned short*)(ws + 39845888);
    unsigned short* qbf  = (unsigned short*)(ws + 39976960);
    unsigned short* kbf  = (unsigned short*)(ws + 56754176);
    unsigned short* vtb  = (unsigned short*)(ws + 73531392);

    convert_f32_bf16_vec<<<8192, 256, 0, stream>>>(x, xb, 2097152);
    transpose_wqkvp<<<dim3(32, 32, 4), 256, 0, stream>>>(Wq, Wk, Wv, Wp, wt, wpt);

    gemm256<<<1024, 512, 0, stream>>>(xb, wt, qbf, kbf, vtb);

    attn_kernel<<<512, 512, 0, stream>>>(qbf, kbf, vtb, ypart);

    gemm_out_fused<<<512, 256, 0, stream>>>(ypart, wpt, out);
}